// Round 9
// baseline (585.111 us; speedup 1.0000x reference)
//
#include <hip/hip_runtime.h>

#define EDGES 400000
#define DIM 128

typedef __attribute__((ext_vector_type(8))) short bf16x8;
typedef __attribute__((ext_vector_type(4))) float f32x4;

// fp32 -> bf16 round-to-nearest-even (no NaN handling needed here)
__device__ __forceinline__ short f2bf(float f) {
    unsigned u = __builtin_bit_cast(unsigned, f);
    unsigned r = (u + 0x7fffu + ((u >> 16) & 1u)) >> 16;
    return (short)r;
}

// Rearrange W1 [768][384] fp32 -> bf16 frag-major for 16x16x32 MFMA B-operand:
// frag (nt, s): lane holds B[k = (lane>>4)*8 + j][n = lane&15], k-step s, n-tile nt.
// W1f[((nt*12+s)*64+lane)*8 + j] = bf16( W1[(nt*16+(lane&15))*384 + s*32+(lane>>4)*8+j] )
__global__ void prep_w1(const float* __restrict__ W1, short* __restrict__ W1f) {
    int idx = blockIdx.x * 256 + threadIdx.x;       // 294912 = 48*12*64*8
    int j    = idx & 7;
    int lane = (idx >> 3) & 63;
    int fs   = idx >> 9;                            // nt*12 + s
    int s    = fs % 12;
    int nt   = fs / 12;
    int n = nt * 16 + (lane & 15);
    int k = s * 32 + (lane >> 4) * 8 + j;
    W1f[idx] = f2bf(W1[n * 384 + k]);
}

// ---- macro-expanded A fragments: 48 NAMED bf16x8 SSA values (no alloca) ----
#define DECL_ROW(T) bf16x8 a##T##_0, a##T##_1, a##T##_2,  a##T##_3,  \
                           a##T##_4, a##T##_5, a##T##_6,  a##T##_7,  \
                           a##T##_8, a##T##_9, a##T##_10, a##T##_11;

#define BUILD_COL(T, I, M0, P0, D0)                                    \
    {                                                                  \
        int c = (I) * 32 + quad * 8;                                   \
        f32x4 v0 = *(const f32x4*)(r0 + c);                            \
        f32x4 v1 = *(const f32x4*)(r0 + c + 4);                        \
        f32x4 w0 = *(const f32x4*)(r1 + c);                            \
        f32x4 w1 = *(const f32x4*)(r1 + c + 4);                        \
        bf16x8 fm, fp, fd;                                             \
        _Pragma("unroll")                                              \
        for (int j = 0; j < 4; ++j) {                                  \
            float aa = v0[j], bb = w0[j];                              \
            fm[j] = f2bf((aa + bb) * 0.5f);                            \
            fp[j] = f2bf(aa * bb);                                     \
            float dd = aa - bb;                                        \
            fd[j] = f2bf(dd * dd);                                     \
            aa = v1[j]; bb = w1[j];                                    \
            fm[j + 4] = f2bf((aa + bb) * 0.5f);                        \
            fp[j + 4] = f2bf(aa * bb);                                 \
            dd = aa - bb;                                              \
            fd[j + 4] = f2bf(dd * dd);                                 \
        }                                                              \
        a##T##_##M0 = fm; a##T##_##P0 = fp; a##T##_##D0 = fd;          \
    }

// sections: cols 0-3 -> mean (k 0..127), prod (k 128..255), sqdiff (k 256..383)
#define BUILD_T(T)                                                     \
    {                                                                  \
        int e = eb + wave * 64 + (T) * 16 + m;                         \
        const float* r0 = x + (size_t)ei[e] * DIM;                     \
        const float* r1 = x + (size_t)ei[EDGES + e] * DIM;             \
        BUILD_COL(T, 0, 0, 4, 8)                                       \
        BUILD_COL(T, 1, 1, 5, 9)                                       \
        BUILD_COL(T, 2, 2, 6, 10)                                      \
        BUILD_COL(T, 3, 3, 7, 11)                                      \
    }

#define MSTEP(S)                                                                        \
    {                                                                                   \
        bf16x8 bf = bp[((S) << 6) + lane];  /* conflict-free: addr = S*1024 + lane*16 */\
        acc0 = __builtin_amdgcn_mfma_f32_16x16x32_bf16(a0_##S, bf, acc0, 0, 0, 0);      \
        acc1 = __builtin_amdgcn_mfma_f32_16x16x32_bf16(a1_##S, bf, acc1, 0, 0, 0);      \
        acc2 = __builtin_amdgcn_mfma_f32_16x16x32_bf16(a2_##S, bf, acc2, 0, 0, 0);      \
        acc3 = __builtin_amdgcn_mfma_f32_16x16x32_bf16(a3_##S, bf, acc3, 0, 0, 0);      \
    }

// Block: 128 threads = 2 waves, 128 edges; each wave owns FOUR M-tiles (64 edges).
// Per-wave LDS B-read is 576 KB regardless of M_w -> 2 waves halves block LDS
// volume vs the 290us 4-wave baseline; each 1KB B-frag feeds 4 MFMAs
// (64 FLOP/LDS-byte) -> MFMA pipe binds (~113us floor), LDS (~70us) hides.
//
// Register budget: rounds 1 & 7 proved both __launch_bounds__(128,2) and
// amdgpu_waves_per_eu(2,2) ALONE leave the allocator at a 4-waves/EU target
// (VGPR_Count=128) and spill the 192-reg A-set (WRITE_SIZE 1.5MB->480MB).
// This version aligns EVERY occupancy input to 2 waves/EU:
//   (a) static LDS padded to 40960B -> LDS-derived occupancy = 4 blocks/CU
//       = 2 waves/SIMD at compile time (runtime residency unchanged: we
//       want 8 waves/CU anyway);
//   (b) amdgpu_waves_per_eu(2,2) kept;
//   (c) afrag array replaced by 48 named SSA values (macro-expanded) so no
//       alloca exists for SROA to miss.
__global__ __launch_bounds__(128) __attribute__((amdgpu_waves_per_eu(2, 2)))
void edge_mlp(const float* __restrict__ x,
              const int*   __restrict__ ei,      // [2][EDGES]
              const float* __restrict__ b1,      // [768]
              const float* __restrict__ W2,      // [768]
              const float* __restrict__ b2p,     // [1]
              const short* __restrict__ W1f,     // frag-major bf16 W1
              float* __restrict__ out)           // [EDGES]
{
    __shared__ short sB[2][12 * 512];            // 2 x 12 frags x 1KB = 24 KB
    __shared__ short sPad[8192];                 // +16 KB occupancy governor -> 40960B total

    // Root sPad so the LDS-size-driven occupancy cap is visible to the compiler.
    asm volatile("" :: "v"((int)(size_t)sPad));

    const int tid  = threadIdx.x;
    const int lane = tid & 63;
    const int wave = tid >> 6;
    const int m    = lane & 15;                  // A-row / B-col / D-col index
    const int quad = lane >> 4;
    const int eb   = blockIdx.x * 128;

    // ---- async stage N-chunk 0 (12 frags; each of the 2 waves issues 6) ----
    #pragma unroll
    for (int jj = 0; jj < 6; ++jj) {
        int s = wave * 6 + jj;
        __builtin_amdgcn_global_load_lds(
            (const __attribute__((address_space(1))) void*)(W1f + (s << 9) + lane * 8),
            (__attribute__((address_space(3))) void*)(&sB[0][s << 9]),
            16, 0, 0);
    }

    // ---- build A fragments: 4 M-tiles x 12 K-steps = 48 named bf16x8 (192 VGPRs) ----
    // A-frag layout (m89/m120-verified): lane holds A[m=lane&15][k=quad*8+j].
    DECL_ROW(0) DECL_ROW(1) DECL_ROW(2) DECL_ROW(3)
    BUILD_T(0) BUILD_T(1) BUILD_T(2) BUILD_T(3)

    f32x4 yp0 = {0.f, 0.f, 0.f, 0.f};
    f32x4 yp1 = {0.f, 0.f, 0.f, 0.f};
    f32x4 yp2 = {0.f, 0.f, 0.f, 0.f};
    f32x4 yp3 = {0.f, 0.f, 0.f, 0.f};

    __syncthreads();   // waits own global_load_lds (vmcnt) then barrier -> chunk 0 ready

    for (int nt = 0; nt < 48; ++nt) {
        const int cur = nt & 1;

        // prefetch next chunk into the other buffer (drains at end-of-iter barrier)
        if (nt + 1 < 48) {
            const short* src = W1f + (size_t)(nt + 1) * 6144;
            #pragma unroll
            for (int jj = 0; jj < 6; ++jj) {
                int s = wave * 6 + jj;
                __builtin_amdgcn_global_load_lds(
                    (const __attribute__((address_space(1))) void*)(src + (s << 9) + lane * 8),
                    (__attribute__((address_space(3))) void*)(&sB[cur ^ 1][s << 9]),
                    16, 0, 0);
            }
        }

        f32x4 acc0 = {0.f, 0.f, 0.f, 0.f};
        f32x4 acc1 = {0.f, 0.f, 0.f, 0.f};
        f32x4 acc2 = {0.f, 0.f, 0.f, 0.f};
        f32x4 acc3 = {0.f, 0.f, 0.f, 0.f};
        const bf16x8* bp = (const bf16x8*)sB[cur];
        MSTEP(0) MSTEP(1) MSTEP(2)  MSTEP(3)
        MSTEP(4) MSTEP(5) MSTEP(6)  MSTEP(7)
        MSTEP(8) MSTEP(9) MSTEP(10) MSTEP(11)

        // epilogue: D layout col=lane&15, row=quad*4+r (m89-verified)
        int ng = nt * 16 + m;
        float bias = b1[ng];
        float w2v  = W2[ng];
        #pragma unroll
        for (int r = 0; r < 4; ++r) {
            yp0[r] = fmaf(fmaxf(acc0[r] + bias, 0.f), w2v, yp0[r]);
            yp1[r] = fmaf(fmaxf(acc1[r] + bias, 0.f), w2v, yp1[r]);
            yp2[r] = fmaf(fmaxf(acc2[r] + bias, 0.f), w2v, yp2[r]);
            yp3[r] = fmaf(fmaxf(acc3[r] + bias, 0.f), w2v, yp3[r]);
        }

        __syncthreads();   // prefetch drained + all waves done reading sB[cur]
    }

    // reduce the 16 columns held across lanes of each quad-group
    #pragma unroll
    for (int off = 8; off >= 1; off >>= 1) {
        #pragma unroll
        for (int r = 0; r < 4; ++r) {
            yp0[r] += __shfl_xor(yp0[r], off, 64);
            yp1[r] += __shfl_xor(yp1[r], off, 64);
            yp2[r] += __shfl_xor(yp2[r], off, 64);
            yp3[r] += __shfl_xor(yp3[r], off, 64);
        }
    }
    if (m == 0) {
        float b2v = b2p[0];
        int e0 = eb + wave * 64 + quad * 4;
        #pragma unroll
        for (int r = 0; r < 4; ++r) {
            out[e0 + r]      = yp0[r] + b2v;
            out[e0 + 16 + r] = yp1[r] + b2v;
            out[e0 + 32 + r] = yp2[r] + b2v;
            out[e0 + 48 + r] = yp3[r] + b2v;
        }
    }
}

extern "C" void kernel_launch(void* const* d_in, const int* in_sizes, int n_in,
                              void* d_out, int out_size, void* d_ws, size_t ws_size,
                              hipStream_t stream) {
    const float* x  = (const float*)d_in[0];
    const int*   ei = (const int*)  d_in[1];
    // d_in[2]=edge_attr3, d_in[3]=edge_attr4, d_in[4]=batch : unused by reference
    const float* W1 = (const float*)d_in[5];
    const float* b1 = (const float*)d_in[6];
    const float* W2 = (const float*)d_in[7];
    const float* b2 = (const float*)d_in[8];
    short* W1f = (short*)d_ws;                 // 589824 B frag-major bf16 W1
    float* out = (float*)d_out;

    prep_w1<<<1152, 256, 0, stream>>>(W1, W1f);            // 294912 elems
    edge_mlp<<<3125, 128, 0, stream>>>(x, ei, b1, W2, b2, W1f, out);
}

// Round 10
// 402.236 us; speedup vs baseline: 1.4546x; 1.4546x over previous
//
#include <hip/hip_runtime.h>

#define EDGES 400000
#define DIM 128

typedef __attribute__((ext_vector_type(8))) short bf16x8;
typedef __attribute__((ext_vector_type(4))) float f32x4;

// fp32 -> bf16 round-to-nearest-even (no NaN handling needed here)
__device__ __forceinline__ short f2bf(float f) {
    unsigned u = __builtin_bit_cast(unsigned, f);
    unsigned r = (u + 0x7fffu + ((u >> 16) & 1u)) >> 16;
    return (short)r;
}

// Rearrange W1 [768][384] fp32 -> bf16 frag-major for 16x16x32 MFMA B-operand:
// frag (nt, s): lane holds B[k = (lane>>4)*8 + j][n = lane&15], k-step s, n-tile nt.
// W1f[((nt*12+s)*64+lane)*8 + j] = bf16( W1[(nt*16+(lane&15))*384 + s*32+(lane>>4)*8+j] )
__global__ void prep_w1(const float* __restrict__ W1, short* __restrict__ W1f) {
    int idx = blockIdx.x * 256 + threadIdx.x;       // 294912 = 48*12*64*8
    int j    = idx & 7;
    int lane = (idx >> 3) & 63;
    int fs   = idx >> 9;                            // nt*12 + s
    int s    = fs % 12;
    int nt   = fs / 12;
    int n = nt * 16 + (lane & 15);
    int k = s * 32 + (lane >> 4) * 8 + j;
    W1f[idx] = f2bf(W1[n * 384 + k]);
}

// One K-step: ds_read B-frag s (conflict-free: addr = s*1024 + lane*16), 2 MFMAs.
// S is a compile-time constant in every expansion -> afrag indices constant (rule #20).
#define MSTEP(S)                                                                          \
    {                                                                                     \
        bf16x8 bf = bp[((S) << 6) + lane];                                                \
        acc0 = __builtin_amdgcn_mfma_f32_16x16x32_bf16(afrag[0][(S)], bf, acc0, 0, 0, 0); \
        acc1 = __builtin_amdgcn_mfma_f32_16x16x32_bf16(afrag[1][(S)], bf, acc1, 0, 0, 0); \
    }

// Rotated K-loop: wave with rotation R consumes s = R, R+1, ..., 11, 0, ..., R-1.
// fp32 accumulation reorder over s only (negligible numerics).
#define KLOOP(R)                                                            \
    MSTEP(((R) + 0) % 12)  MSTEP(((R) + 1) % 12)  MSTEP(((R) + 2) % 12)     \
    MSTEP(((R) + 3) % 12)  MSTEP(((R) + 4) % 12)  MSTEP(((R) + 5) % 12)     \
    MSTEP(((R) + 6) % 12)  MSTEP(((R) + 7) % 12)  MSTEP(((R) + 8) % 12)     \
    MSTEP(((R) + 9) % 12)  MSTEP(((R) + 10) % 12) MSTEP(((R) + 11) % 12)

// Block: 256 threads = 4 waves, 128 edges (each wave owns 2 M-tiles of 16 edges).
// This is the proven 290us round-0 structure (96-VGPR afrag, fits the 128-reg
// budget the allocator enforces; rounds 1/7/9 proved it refuses 192-reg A-sets:
// VGPR_Count pinned at 128 + 476MB scratch spill through every waves-per-eu
// mechanism). The remaining limiter per round-0 PMC arithmetic: per CU per nt,
// LDS = 2304cy and MFMA = 1862cy but measured period = 4756cy ~= the SERIAL sum
// -> CU-wide 2-phase lockstep (all waves read then all waves MFMA, m233 stall).
// Fix (T3-lite + T5): per-wave K-step ROTATION (wave w starts at s=3w, via
// compile-time switch) de-phases the waves so ds_read and MFMA pipes overlap
// across waves; s_setprio(1) around compute lets the scheduler prefer
// MFMA-issuing waves now that wave roles differ.
__global__ __launch_bounds__(256, 2)
void edge_mlp(const float* __restrict__ x,
              const int*   __restrict__ ei,      // [2][EDGES]
              const float* __restrict__ b1,      // [768]
              const float* __restrict__ W2,      // [768]
              const float* __restrict__ b2p,     // [1]
              const short* __restrict__ W1f,     // frag-major bf16 W1
              float* __restrict__ out)           // [EDGES]
{
    __shared__ short sB[2][12 * 512];            // 2 x 12 frags x 1KB = 24 KB

    const int tid  = threadIdx.x;
    const int lane = tid & 63;
    const int wave = tid >> 6;
    const int m    = lane & 15;                  // A-row / B-col / D-col index
    const int quad = lane >> 4;
    const int eb   = blockIdx.x * 128;

    // ---- async stage N-chunk 0 (12 frags; each wave issues 3) ----
    #pragma unroll
    for (int jj = 0; jj < 3; ++jj) {
        int s = wave * 3 + jj;
        __builtin_amdgcn_global_load_lds(
            (const __attribute__((address_space(1))) void*)(W1f + (s << 9) + lane * 8),
            (__attribute__((address_space(3))) void*)(&sB[0][s << 9]),
            16, 0, 0);
    }

    // ---- build A fragments in registers: 2 M-tiles x 12 K-steps (96 VGPRs) ----
    // A-frag layout (m89/m120-verified): lane holds A[m=lane&15][k=quad*8+j].
    // feat col kc = 32*s + 8*quad + j ; sections: s 0-3 mean, 4-7 prod, 8-11 sqdiff,
    // all three from the SAME x columns -> each x chunk loaded once.
    bf16x8 afrag[2][12];
    #pragma unroll
    for (int T = 0; T < 2; ++T) {
        int e = eb + wave * 32 + T * 16 + m;
        const float* r0 = x + (size_t)ei[e] * DIM;
        const float* r1 = x + (size_t)ei[EDGES + e] * DIM;
        #pragma unroll
        for (int i = 0; i < 4; ++i) {
            int c = i * 32 + quad * 8;
            f32x4 a0 = *(const f32x4*)(r0 + c);
            f32x4 a1 = *(const f32x4*)(r0 + c + 4);
            f32x4 c0 = *(const f32x4*)(r1 + c);
            f32x4 c1 = *(const f32x4*)(r1 + c + 4);
            bf16x8 fm, fp, fd;
            #pragma unroll
            for (int j = 0; j < 4; ++j) {
                float aa = a0[j], bb = c0[j];
                fm[j] = f2bf((aa + bb) * 0.5f);
                fp[j] = f2bf(aa * bb);
                float dd = aa - bb;
                fd[j] = f2bf(dd * dd);
                aa = a1[j]; bb = c1[j];
                fm[j + 4] = f2bf((aa + bb) * 0.5f);
                fp[j + 4] = f2bf(aa * bb);
                dd = aa - bb;
                fd[j + 4] = f2bf(dd * dd);
            }
            afrag[T][i]     = fm;   // mean      -> k in [0,128)
            afrag[T][i + 4] = fp;   // product   -> k in [128,256)
            afrag[T][i + 8] = fd;   // sq. diff  -> k in [256,384)
        }
    }

    float yp0[4] = {0.f, 0.f, 0.f, 0.f};
    float yp1[4] = {0.f, 0.f, 0.f, 0.f};

    __syncthreads();   // waits own global_load_lds (vmcnt) then barrier -> chunk 0 ready

    for (int nt = 0; nt < 48; ++nt) {
        const int cur = nt & 1;

        // prefetch next chunk into the other buffer (drains at end-of-iter barrier)
        if (nt + 1 < 48) {
            const short* src = W1f + (size_t)(nt + 1) * 6144;
            #pragma unroll
            for (int jj = 0; jj < 3; ++jj) {
                int s = wave * 3 + jj;
                __builtin_amdgcn_global_load_lds(
                    (const __attribute__((address_space(1))) void*)(src + (s << 9) + lane * 8),
                    (__attribute__((address_space(3))) void*)(&sB[cur ^ 1][s << 9]),
                    16, 0, 0);
            }
        }

        f32x4 acc0 = {0.f, 0.f, 0.f, 0.f};
        f32x4 acc1 = {0.f, 0.f, 0.f, 0.f};
        const bf16x8* bp = (const bf16x8*)sB[cur];

        // staggered compute phase: wave w starts at s = 3w (wave-uniform branch,
        // no divergence; each arm fully unrolled with constant afrag indices)
        __builtin_amdgcn_s_setprio(1);
        switch (wave) {
            case 0: { KLOOP(0) } break;
            case 1: { KLOOP(3) } break;
            case 2: { KLOOP(6) } break;
            default: { KLOOP(9) } break;
        }
        __builtin_amdgcn_s_setprio(0);

        // epilogue: D layout col=lane&15, row=quad*4+r (m89-verified)
        int ng = nt * 16 + m;
        float bias = b1[ng];
        float w2v  = W2[ng];
        #pragma unroll
        for (int r = 0; r < 4; ++r) {
            float h0 = acc0[r] + bias;
            float h1 = acc1[r] + bias;
            yp0[r] = fmaf(fmaxf(h0, 0.f), w2v, yp0[r]);
            yp1[r] = fmaf(fmaxf(h1, 0.f), w2v, yp1[r]);
        }

        __syncthreads();   // prefetch drained + all waves done reading sB[cur]
    }

    // reduce the 16 columns held across lanes of each quad-group
    #pragma unroll
    for (int off = 8; off >= 1; off >>= 1) {
        #pragma unroll
        for (int r = 0; r < 4; ++r) {
            yp0[r] += __shfl_xor(yp0[r], off, 64);
            yp1[r] += __shfl_xor(yp1[r], off, 64);
        }
    }
    if (m == 0) {
        float b2v = b2p[0];
        int e0 = eb + wave * 32 + quad * 4;
        #pragma unroll
        for (int r = 0; r < 4; ++r) {
            out[e0 + r]      = yp0[r] + b2v;
            out[e0 + 16 + r] = yp1[r] + b2v;
        }
    }
}

extern "C" void kernel_launch(void* const* d_in, const int* in_sizes, int n_in,
                              void* d_out, int out_size, void* d_ws, size_t ws_size,
                              hipStream_t stream) {
    const float* x  = (const float*)d_in[0];
    const int*   ei = (const int*)  d_in[1];
    // d_in[2]=edge_attr3, d_in[3]=edge_attr4, d_in[4]=batch : unused by reference
    const float* W1 = (const float*)d_in[5];
    const float* b1 = (const float*)d_in[6];
    const float* W2 = (const float*)d_in[7];
    const float* b2 = (const float*)d_in[8];
    short* W1f = (short*)d_ws;                 // 589824 B frag-major bf16 W1
    float* out = (float*)d_out;

    prep_w1<<<1152, 256, 0, stream>>>(W1, W1f);            // 294912 elems
    edge_mlp<<<3125, 256, 0, stream>>>(x, ei, b1, W2, b2, W1f, out);
}